// Round 16
// baseline (2317.040 us; speedup 1.0000x reference)
//
#include <hip/hip_runtime.h>

#define NB 32
#define NP 65536
#define NS 1024
#define NT 1024
#define BPB 8                 // blocks per batch (proven best, R7)
#define CHUNK (NP / BPB)      // 8192 points per block
#define PPT (CHUNK / NT)      // 8 points per thread

typedef unsigned long long u64;
typedef unsigned int u32;
typedef int int4v __attribute__((ext_vector_type(4)));
typedef float f2 __attribute__((ext_vector_type(2)));

// ---------------- R16: R15 + single barrier/iter (LDS qtag handoff) ---------
// Exchange protocol = R7 verbatim (2222us floor across 8 variants); compute =
// R15 packed-f32 (v_pk_*, verified −90us). New: only ONE __syncthreads per
// iteration (before stage-2, guarding cand[par]); q is handed to waves 1-15
// via a volatile LDS tag + threadfence_block instead of a second barrier.
// Wave0 gets q fully in-register (shfl broadcast — R13-verified pattern).
// Deadlock audit: wave0 never spins on LDS (no intra-wave writer/spinner
// divergence = R8/R9 trap); waves 1-15's qtag spin terminates because wave0's
// qtag write follows its R7-proven-terminating slot poll; cand parity
// double-buffer makes the single barrier sufficient (next write hits par^1).
__global__ __launch_bounds__(NT) void fps_v16(const float* __restrict__ pts,
                                              float* __restrict__ out,
                                              u32* __restrict__ slots) {
#pragma clang fp contract(off)
    const int bid = blockIdx.x;
    const int b = bid >> 3;           // batch: consecutive bids (R7 mapping)
    const int j = bid & 7;
    const int t = threadIdx.x;
    const int wave = t >> 6;
    const int lane = t & 63;
    const int base = j * CHUNK;
    const float* __restrict__ pb = pts + (size_t)b * NP * 3;
    float* __restrict__ out_idx = out + (size_t)b * NS;
    float* __restrict__ out_pts = out + (size_t)NB * NS + (size_t)b * NS * 3;
    u32* __restrict__ slot_b = slots + (size_t)b * NS * BPB * 8;  // u32 words

    __shared__ float P[CHUNK * 3];    // 96 KB packed points
    __shared__ u64 cand[2][NT / 64];  // parity double-buffer
    __shared__ int sel_hist[NS];
    __shared__ float qsh[3];
    __shared__ int qtag;              // handoff tag: ==s when qsh holds q_s

    // stage chunk into LDS, coalesced float4
    {
        const float4* __restrict__ src4 = (const float4*)(pb + (size_t)base * 3);
        float4* dst4 = (float4*)P;
#pragma unroll
        for (int k = 0; k < (CHUNK * 3 / 4) / NT; ++k) dst4[t + k * NT] = src4[t + k * NT];
    }
    if (t == 0) {
        sel_hist[0] = 0;
        qtag = 0;
        if (j == 0) out_idx[0] = 0.0f;
    }
    __syncthreads();

    // points -> registers, CONSECUTIVE range [t*8, t*8+8), packed 2/reg:
    // lowest lane == lowest global idx (exact ballot tie-break, R10-R15)
    f2 PX[PPT / 2], PY[PPT / 2], PZ[PPT / 2], MD[PPT / 2];
#pragma unroll
    for (int i = 0; i < PPT / 2; ++i) {
        const int li = t * PPT + 2 * i;
        PX[i].x = P[li * 3 + 0];  PX[i].y = P[li * 3 + 3];
        PY[i].x = P[li * 3 + 1];  PY[i].y = P[li * 3 + 4];
        PZ[i].x = P[li * 3 + 2];  PZ[i].y = P[li * 3 + 5];
        MD[i] = (f2){1e10f, 1e10f};
    }
    float qx = pb[0], qy = pb[1], qz = pb[2];   // first sel = point 0

    for (int s = 1; s < NS; ++s) {
        const int par = s & 1;
        const f2 q2x = {qx, qx}, q2y = {qy, qy}, q2z = {qz, qz};
        float nmv[PPT];
#pragma unroll
        for (int i = 0; i < PPT / 2; ++i) {
            f2 dx = PX[i] - q2x;              // v_pk_add_f32 (neg modifier)
            f2 dy = PY[i] - q2y;
            f2 dz = PZ[i] - q2z;
            f2 d = (dx * dx + dy * dy) + dz * dz;   // pk_mul/pk_add, np order
            f2 nm;
            nm.x = fminf(MD[i].x, d.x);
            nm.y = fminf(MD[i].y, d.y);
            MD[i] = nm;
            nmv[2 * i] = nm.x;
            nmv[2 * i + 1] = nm.y;
        }
        float bv = fmaxf(fmaxf(fmaxf(nmv[0], nmv[1]), fmaxf(nmv[2], nmv[3])),
                         fmaxf(fmaxf(nmv[4], nmv[5]), fmaxf(nmv[6], nmv[7])));
        // wave argmax: f32 max reduce; ballot lowest lane among ties == min idx
        float m = bv;
#pragma unroll
        for (int d1 = 32; d1 >= 1; d1 >>= 1) m = fmaxf(m, __shfl_xor(m, d1, 64));
        u64 msk = __ballot(bv == m);
        int src = __ffsll((unsigned long long)msk) - 1;
        int kk = PPT - 1;
#pragma unroll
        for (int k2 = PPT - 2; k2 >= 0; --k2) kk = (nmv[k2] == bv) ? k2 : kk;
        int biw = __shfl(t * PPT + kk, src, 64);
        if (lane == 0)
            cand[par][wave] = ((u64)__float_as_uint(m) << 32) |
                              (u64)(0xFFFFFFFFu - (u32)(base + biw));
        __syncthreads();                   // the ONLY barrier per iteration
        if (wave == 0) {
            // stage-2: reduce the 16 wave candidates
            u64 c = cand[par][lane & 15];
#pragma unroll
            for (int d1 = 8; d1 >= 1; d1 >>= 1) {
                u64 o = __shfl_xor(c, d1, 64);
                c = (o > c) ? o : c;
            }
            // ---- writer: separate, loop-free, completes before polls ----
            if (lane == 0) {
                const int lw = (int)(0xFFFFFFFFu - (u32)c) - base;
                int4v h0, h1;
                h0.x = (int)(u32)c;               // key lo = ~gidx != 0
                h0.y = (int)(u32)(c >> 32);       // key hi = valbits
                h0.z = __float_as_int(P[lw * 3 + 0]);
                h0.w = __float_as_int(P[lw * 3 + 1]);
                h1.x = h0.x;
                h1.y = h0.y;
                h1.z = __float_as_int(P[lw * 3 + 2]);
                h1.w = 0;
                u32* sp = slot_b + ((size_t)s * BPB + j) * 8;
                asm volatile(
                    "global_store_dwordx4 %0, %2, off sc0 sc1\n\t"
                    "global_store_dwordx4 %1, %3, off sc0 sc1"
                    :: "v"(sp), "v"(sp + 4), "v"(h0), "v"(h1) : "memory");
            }
            // ---- pollers: plain R7 sc0sc1 loop (lanes 0-7, skip own j) ----
            u64 k = c;
            float wx = 0.f, wy = 0.f, wz = 0.f;
            if (lane < BPB && lane != j) {
                const u32* sp = slot_b + ((size_t)s * BPB + lane) * 8;
                int4v a, bb;
                for (;;) {
                    asm volatile(
                        "global_load_dwordx4 %0, %2, off sc0 sc1\n\t"
                        "global_load_dwordx4 %1, %3, off sc0 sc1\n\t"
                        "s_waitcnt vmcnt(0)"
                        : "=&v"(a), "=&v"(bb)
                        : "v"(sp), "v"(sp + 4) : "memory");
                    if (a.x != 0 && a.x == bb.x && a.y == bb.y) break;
                }
                k = ((u64)(u32)a.y << 32) | (u32)a.x;
                wx = __int_as_float(a.z);
                wy = __int_as_float(a.w);
                wz = __int_as_float(bb.z);
            }
            // reduce lanes 0-7, then full-wave broadcast (R13 pattern)
#pragma unroll
            for (int d1 = 4; d1 >= 1; d1 >>= 1) {
                u64 o = __shfl_xor(k, d1, 64);
                k = (o > k) ? o : k;
            }
            k = __shfl(k, 0, 64);              // all 64 lanes of wave0
            const int g = (int)(0xFFFFFFFFu - (u32)(k & 0xFFFFFFFFull));
            const int jw = (g >> 13) & 7;      // owning block (CHUNK=2^13)
            if (jw == j) {
                const int lw = g - base;       // uniform LDS read (broadcast)
                qx = P[lw * 3 + 0];
                qy = P[lw * 3 + 1];
                qz = P[lw * 3 + 2];
            } else {
                qx = __shfl(wx, jw, 64);
                qy = __shfl(wy, jw, 64);
                qz = __shfl(wz, jw, 64);
            }
            if (lane == 0) {
                sel_hist[s] = g;
                if (j == 0) out_idx[s] = (float)g;
                qsh[0] = qx; qsh[1] = qy; qsh[2] = qz;
                __threadfence_block();         // qsh visible before tag
                qtag = s;                      // release waves 1-15
            }
        } else {
            // waves 1-15: LDS spin until q_s published (terminates: wave0's
            // qtag write follows its R7-proven-terminating poll)
            while (*(volatile int*)&qtag != s) __builtin_amdgcn_s_sleep(1);
            __threadfence_block();
            qx = qsh[0]; qy = qsh[1]; qz = qsh[2];
        }
    }

    __syncthreads();
    if (j == 0) {
        const int gi = sel_hist[t];
        const float* __restrict__ p = pb + (size_t)gi * 3;
        out_pts[(size_t)t * 3 + 0] = p[0];
        out_pts[(size_t)t * 3 + 1] = p[1];
        out_pts[(size_t)t * 3 + 2] = p[2];
    }
}

// ---------------- fallback (no workspace): 1 block/batch --------------------
__global__ __launch_bounds__(NT) void fps_single(const float* __restrict__ pts,
                                                 float* __restrict__ out) {
#pragma clang fp contract(off)
    const int b = blockIdx.x;
    const int t = threadIdx.x;
    const float* __restrict__ pb = pts + (size_t)b * NP * 3;
    float* __restrict__ out_idx = out + (size_t)b * NS;
    float* __restrict__ out_pts = out + (size_t)NB * NS + (size_t)b * NS * 3;
    __shared__ int sel_hist[NS];
    __shared__ u64 cand[16];
    __shared__ int sel_sh;
    float md[NP / NT];
#pragma unroll
    for (int i = 0; i < NP / NT; ++i) md[i] = 1e10f;
    if (t == 0) { sel_hist[0] = 0; out_idx[0] = 0.0f; }
    float qx = pb[0], qy = pb[1], qz = pb[2];
    const int wave = t >> 6;
    const int lane = t & 63;
    for (int s = 1; s < NS; ++s) {
        float bestv = -1.0f;
        int besti = 0;
#pragma unroll
        for (int i = 0; i < NP / NT; ++i) {
            const int gi = t + i * NT;
            const float* __restrict__ p = pb + (size_t)gi * 3;
            float dx = p[0] - qx, dy = p[1] - qy, dz = p[2] - qz;
            float d = (dx * dx + dy * dy) + dz * dz;
            float nmd = fminf(md[i], d);
            md[i] = nmd;
            if (nmd > bestv) { bestv = nmd; besti = gi; }
        }
        u64 pk = ((u64)__float_as_uint(bestv) << 32) |
                 (u64)(0xFFFFFFFFu - (u32)besti);
#pragma unroll
        for (int m = 32; m >= 1; m >>= 1) {
            u64 o = __shfl_xor(pk, m, 64);
            pk = (o > pk) ? o : pk;
        }
        if (lane == 0) cand[wave] = pk;
        __syncthreads();
        if (wave == 0) {
            u64 c = (lane < 16) ? cand[lane] : 0ull;
#pragma unroll
            for (int m = 8; m >= 1; m >>= 1) {
                u64 o = __shfl_xor(c, m, 64);
                c = (o > c) ? o : c;
            }
            if (lane == 0) {
                int w = (int)(0xFFFFFFFFu - (u32)(c & 0xFFFFFFFFull));
                sel_sh = w; sel_hist[s] = w; out_idx[s] = (float)w;
            }
        }
        __syncthreads();
        const int sel = sel_sh;
        qx = pb[(size_t)sel * 3]; qy = pb[(size_t)sel * 3 + 1]; qz = pb[(size_t)sel * 3 + 2];
    }
    __syncthreads();
    {
        const int gi = sel_hist[t];
        const float* __restrict__ p = pb + (size_t)gi * 3;
        out_pts[(size_t)t * 3 + 0] = p[0];
        out_pts[(size_t)t * 3 + 1] = p[1];
        out_pts[(size_t)t * 3 + 2] = p[2];
    }
}

extern "C" void kernel_launch(void* const* d_in, const int* in_sizes, int n_in,
                              void* d_out, int out_size, void* d_ws, size_t ws_size,
                              hipStream_t stream) {
    const float* pts = (const float*)d_in[0];
    float* out = (float*)d_out;
    (void)in_sizes; (void)n_in; (void)out_size;

    const size_t v16_bytes = (size_t)NB * NS * BPB * 32;   // 8 MB
    if (ws_size >= v16_bytes) {
        u32* slots = (u32*)d_ws;
        hipMemsetAsync(d_ws, 0, v16_bytes, stream);
        void* args[] = {(void*)&pts, (void*)&out, (void*)&slots};
        hipLaunchCooperativeKernel((const void*)fps_v16, dim3(NB * BPB), dim3(NT),
                                   args, 0, stream);
    } else {
        hipLaunchKernelGGL(fps_single, dim3(NB), dim3(NT), 0, stream, pts, out);
    }
}

// Round 17
// 2135.662 us; speedup vs baseline: 1.0849x; 1.0849x over previous
//
#include <hip/hip_runtime.h>

#define NB 32
#define NP 65536
#define NS 1024
#define NT 1024
#define BPB 8                 // blocks per batch (proven best, R7)
#define CHUNK (NP / BPB)      // 8192 points per block
#define PPT (CHUNK / NT)      // 8 points per thread

typedef unsigned long long u64;
typedef unsigned int u32;
typedef int int4v __attribute__((ext_vector_type(4)));
typedef float f2 __attribute__((ext_vector_type(2)));

// ---------------- R17 = R15 verbatim (proven 2134us best) -------------------
// Exchange = R7 protocol (floor across 9 variants): per-s write-once 32B
// slots, h0={keylo,keyhi,x,y} h1={keylo,keyhi,z,0}, valid iff keylo!=0 &&
// h0.key==h1.key; all slot ops sc0 sc1 (cached polls go stale; LLC polls are
// latency-bound — hotness/pipelining/extra pollers/LDS-handoff all lose).
// Compute = packed-f32 inner loop (v_pk_add/mul, bit-exact, -90us).
// CONTROL FLOW (R8/R9 rule): slot store is straight-line lane-0 code that
// completes before any poll loop starts.
__global__ __launch_bounds__(NT) void fps_v15(const float* __restrict__ pts,
                                              float* __restrict__ out,
                                              u32* __restrict__ slots) {
#pragma clang fp contract(off)
    const int bid = blockIdx.x;
    const int b = bid >> 3;           // batch: consecutive bids (R7 mapping)
    const int j = bid & 7;
    const int t = threadIdx.x;
    const int wave = t >> 6;
    const int lane = t & 63;
    const int base = j * CHUNK;
    const float* __restrict__ pb = pts + (size_t)b * NP * 3;
    float* __restrict__ out_idx = out + (size_t)b * NS;
    float* __restrict__ out_pts = out + (size_t)NB * NS + (size_t)b * NS * 3;
    u32* __restrict__ slot_b = slots + (size_t)b * NS * BPB * 8;  // u32 words

    __shared__ float P[CHUNK * 3];    // 96 KB packed points
    __shared__ u64 cand[NT / 64];
    __shared__ int sel_hist[NS];
    __shared__ float qsh[3];

    // stage chunk into LDS, coalesced float4
    {
        const float4* __restrict__ src4 = (const float4*)(pb + (size_t)base * 3);
        float4* dst4 = (float4*)P;
#pragma unroll
        for (int k = 0; k < (CHUNK * 3 / 4) / NT; ++k) dst4[t + k * NT] = src4[t + k * NT];
    }
    if (t == 0) {
        sel_hist[0] = 0;
        if (j == 0) out_idx[0] = 0.0f;
        qsh[0] = pb[0]; qsh[1] = pb[1]; qsh[2] = pb[2];   // first sel = point 0
    }
    __syncthreads();

    // points -> registers, CONSECUTIVE range [t*8, t*8+8), packed 2/reg:
    // lowest lane == lowest global idx (exact ballot tie-break, R10-R15)
    f2 PX[PPT / 2], PY[PPT / 2], PZ[PPT / 2], MD[PPT / 2];
#pragma unroll
    for (int i = 0; i < PPT / 2; ++i) {
        const int li = t * PPT + 2 * i;
        PX[i].x = P[li * 3 + 0];  PX[i].y = P[li * 3 + 3];
        PY[i].x = P[li * 3 + 1];  PY[i].y = P[li * 3 + 4];
        PZ[i].x = P[li * 3 + 2];  PZ[i].y = P[li * 3 + 5];
        MD[i] = (f2){1e10f, 1e10f};
    }
    float qx = qsh[0], qy = qsh[1], qz = qsh[2];

    for (int s = 1; s < NS; ++s) {
        const f2 q2x = {qx, qx}, q2y = {qy, qy}, q2z = {qz, qz};
        float nmv[PPT];
#pragma unroll
        for (int i = 0; i < PPT / 2; ++i) {
            f2 dx = PX[i] - q2x;              // v_pk_add_f32 (neg modifier)
            f2 dy = PY[i] - q2y;
            f2 dz = PZ[i] - q2z;
            f2 d = (dx * dx + dy * dy) + dz * dz;   // pk_mul/pk_add, np order
            f2 nm;
            nm.x = fminf(MD[i].x, d.x);
            nm.y = fminf(MD[i].y, d.y);
            MD[i] = nm;
            nmv[2 * i] = nm.x;
            nmv[2 * i + 1] = nm.y;
        }
        // per-thread max (tree; fmax pairs fuse to v_max3)
        float bv = fmaxf(fmaxf(fmaxf(nmv[0], nmv[1]), fmaxf(nmv[2], nmv[3])),
                         fmaxf(fmaxf(nmv[4], nmv[5]), fmaxf(nmv[6], nmv[7])));
        // wave argmax: f32 max reduce; ballot lowest lane among ties == min idx
        float m = bv;
#pragma unroll
        for (int d1 = 32; d1 >= 1; d1 >>= 1) m = fmaxf(m, __shfl_xor(m, d1, 64));
        u64 msk = __ballot(bv == m);
        int src = __ffsll((unsigned long long)msk) - 1;
        // lowest local k with nmv[k]==bv (reverse scan; == in-loop strict->)
        int kk = PPT - 1;
#pragma unroll
        for (int k2 = PPT - 2; k2 >= 0; --k2) kk = (nmv[k2] == bv) ? k2 : kk;
        int biw = __shfl(t * PPT + kk, src, 64);
        if (lane == 0)
            cand[wave] = ((u64)__float_as_uint(m) << 32) |
                         (u64)(0xFFFFFFFFu - (u32)(base + biw));
        __syncthreads();
        if (wave == 0) {
            // stage-2: all lanes reduce the 16 wave candidates
            u64 c = cand[lane & 15];
#pragma unroll
            for (int d1 = 8; d1 >= 1; d1 >>= 1) {
                u64 o = __shfl_xor(c, d1, 64);
                c = (o > c) ? o : c;
            }
            // ---- writer: separate, loop-free, completes before polls ----
            const int g0 = (int)(0xFFFFFFFFu - (u32)(c & 0xFFFFFFFFull));
            float wx0 = 0.f, wy0 = 0.f, wz0 = 0.f;
            if (lane == 0) {
                const int lw = g0 - base;
                wx0 = P[lw * 3 + 0];
                wy0 = P[lw * 3 + 1];
                wz0 = P[lw * 3 + 2];
                int4v h0, h1;
                h0.x = (int)(u32)(c & 0xFFFFFFFFull);   // key lo = ~gidx != 0
                h0.y = (int)(u32)(c >> 32);             // key hi = valbits
                h0.z = __float_as_int(wx0);
                h0.w = __float_as_int(wy0);
                h1.x = h0.x;
                h1.y = h0.y;
                h1.z = __float_as_int(wz0);
                h1.w = 0;
                u32* sp = slot_b + ((size_t)s * BPB + j) * 8;
                asm volatile(
                    "global_store_dwordx4 %0, %2, off sc0 sc1\n\t"
                    "global_store_dwordx4 %1, %3, off sc0 sc1"
                    :: "v"(sp), "v"(sp + 4), "v"(h0), "v"(h1) : "memory");
            }
            // ---- pollers: plain R7 sc0sc1 loop ----
            if (lane < BPB) {
                u64 k = c;                        // lane j keeps own candidate
                float wx = 0.f, wy = 0.f, wz = 0.f;
                if (lane != j) {
                    const u32* sp = slot_b + ((size_t)s * BPB + lane) * 8;
                    int4v a, bb;
                    for (;;) {
                        asm volatile(
                            "global_load_dwordx4 %0, %2, off sc0 sc1\n\t"
                            "global_load_dwordx4 %1, %3, off sc0 sc1\n\t"
                            "s_waitcnt vmcnt(0)"
                            : "=&v"(a), "=&v"(bb)
                            : "v"(sp), "v"(sp + 4) : "memory");
                        if (a.x != 0 && a.x == bb.x && a.y == bb.y) break;
                    }
                    k = ((u64)(u32)a.y << 32) | (u32)a.x;
                    wx = __int_as_float(a.z);
                    wy = __int_as_float(a.w);
                    wz = __int_as_float(bb.z);
                }
                // reduce over the 8 participants (lanes 0-7)
#pragma unroll
                for (int d1 = 4; d1 >= 1; d1 >>= 1) {
                    u64 o = __shfl_xor(k, d1, 64);
                    k = (o > k) ? o : k;
                }
                const int g = (int)(0xFFFFFFFFu - (u32)(k & 0xFFFFFFFFull));
                const int jw = (g >> 13) & 7;      // owning block (CHUNK=2^13)
                float sx = __shfl(wx, jw, 64);
                float sy = __shfl(wy, jw, 64);
                float sz = __shfl(wz, jw, 64);
                if (lane == 0) {
                    sel_hist[s] = g;
                    if (jw == j) { qsh[0] = wx0; qsh[1] = wy0; qsh[2] = wz0; }
                    else         { qsh[0] = sx;  qsh[1] = sy;  qsh[2] = sz;  }
                    if (j == 0) out_idx[s] = (float)g;
                }
            }
        }
        __syncthreads();
        qx = qsh[0]; qy = qsh[1]; qz = qsh[2];
    }

    if (j == 0) {
        const int gi = sel_hist[t];
        const float* __restrict__ p = pb + (size_t)gi * 3;
        out_pts[(size_t)t * 3 + 0] = p[0];
        out_pts[(size_t)t * 3 + 1] = p[1];
        out_pts[(size_t)t * 3 + 2] = p[2];
    }
}

// ---------------- fallback (no workspace): 1 block/batch --------------------
__global__ __launch_bounds__(NT) void fps_single(const float* __restrict__ pts,
                                                 float* __restrict__ out) {
#pragma clang fp contract(off)
    const int b = blockIdx.x;
    const int t = threadIdx.x;
    const float* __restrict__ pb = pts + (size_t)b * NP * 3;
    float* __restrict__ out_idx = out + (size_t)b * NS;
    float* __restrict__ out_pts = out + (size_t)NB * NS + (size_t)b * NS * 3;
    __shared__ int sel_hist[NS];
    __shared__ u64 cand[16];
    __shared__ int sel_sh;
    float md[NP / NT];
#pragma unroll
    for (int i = 0; i < NP / NT; ++i) md[i] = 1e10f;
    if (t == 0) { sel_hist[0] = 0; out_idx[0] = 0.0f; }
    float qx = pb[0], qy = pb[1], qz = pb[2];
    const int wave = t >> 6;
    const int lane = t & 63;
    for (int s = 1; s < NS; ++s) {
        float bestv = -1.0f;
        int besti = 0;
#pragma unroll
        for (int i = 0; i < NP / NT; ++i) {
            const int gi = t + i * NT;
            const float* __restrict__ p = pb + (size_t)gi * 3;
            float dx = p[0] - qx, dy = p[1] - qy, dz = p[2] - qz;
            float d = (dx * dx + dy * dy) + dz * dz;
            float nmd = fminf(md[i], d);
            md[i] = nmd;
            if (nmd > bestv) { bestv = nmd; besti = gi; }
        }
        u64 pk = ((u64)__float_as_uint(bestv) << 32) |
                 (u64)(0xFFFFFFFFu - (u32)besti);
#pragma unroll
        for (int m = 32; m >= 1; m >>= 1) {
            u64 o = __shfl_xor(pk, m, 64);
            pk = (o > pk) ? o : pk;
        }
        if (lane == 0) cand[wave] = pk;
        __syncthreads();
        if (wave == 0) {
            u64 c = (lane < 16) ? cand[lane] : 0ull;
#pragma unroll
            for (int m = 8; m >= 1; m >>= 1) {
                u64 o = __shfl_xor(c, m, 64);
                c = (o > c) ? o : c;
            }
            if (lane == 0) {
                int w = (int)(0xFFFFFFFFu - (u32)(c & 0xFFFFFFFFull));
                sel_sh = w; sel_hist[s] = w; out_idx[s] = (float)w;
            }
        }
        __syncthreads();
        const int sel = sel_sh;
        qx = pb[(size_t)sel * 3]; qy = pb[(size_t)sel * 3 + 1]; qz = pb[(size_t)sel * 3 + 2];
    }
    __syncthreads();
    {
        const int gi = sel_hist[t];
        const float* __restrict__ p = pb + (size_t)gi * 3;
        out_pts[(size_t)t * 3 + 0] = p[0];
        out_pts[(size_t)t * 3 + 1] = p[1];
        out_pts[(size_t)t * 3 + 2] = p[2];
    }
}

extern "C" void kernel_launch(void* const* d_in, const int* in_sizes, int n_in,
                              void* d_out, int out_size, void* d_ws, size_t ws_size,
                              hipStream_t stream) {
    const float* pts = (const float*)d_in[0];
    float* out = (float*)d_out;
    (void)in_sizes; (void)n_in; (void)out_size;

    const size_t v15_bytes = (size_t)NB * NS * BPB * 32;   // 8 MB
    if (ws_size >= v15_bytes) {
        u32* slots = (u32*)d_ws;
        hipMemsetAsync(d_ws, 0, v15_bytes, stream);
        void* args[] = {(void*)&pts, (void*)&out, (void*)&slots};
        hipLaunchCooperativeKernel((const void*)fps_v15, dim3(NB * BPB), dim3(NT),
                                   args, 0, stream);
    } else {
        hipLaunchKernelGGL(fps_single, dim3(NB), dim3(NT), 0, stream, pts, out);
    }
}